// Round 1
// baseline (1000.767 us; speedup 1.0000x reference)
//
#include <hip/hip_runtime.h>
#include <hip/hip_bf16.h>

#define N_TOK 4096
#define DIM   1024
#define HID   4096
#define NEXP  8
#define KSEL  2

#define BM 128
#define BN 128
#define BK 32
#define LDK 40   // padded LDS stride in shorts (32 + 8)
#define MAXT 72  // max m-tiles: 8192/128 + 8 experts

typedef float  f32x4  __attribute__((ext_vector_type(4)));
typedef __bf16 bf16x8 __attribute__((ext_vector_type(8)));

__device__ __forceinline__ unsigned short f2bf(float f) {
  __hip_bfloat16 h = __float2bfloat16(f);
  return *reinterpret_cast<unsigned short*>(&h);
}

// ---------------- gating: scores, top-2, softmax ----------------
__global__ __launch_bounds__(256) void gate_kernel(
    const float* __restrict__ x, const float* __restrict__ Wg,
    const float* __restrict__ bg, int* __restrict__ topk_idx,
    float* __restrict__ topk_w, int* __restrict__ expert_count)
{
  const int wave = threadIdx.x >> 6, lane = threadIdx.x & 63;
  const int t = blockIdx.x * 4 + wave;
  const float* xr = x + (size_t)t * DIM;

  float acc[NEXP];
#pragma unroll
  for (int e = 0; e < NEXP; e++) acc[e] = 0.f;

  for (int d = lane; d < DIM; d += 64) {
    float xv = xr[d];
    const f32x4* wr = reinterpret_cast<const f32x4*>(Wg + (size_t)d * NEXP);
    f32x4 w0 = wr[0], w1 = wr[1];
    acc[0] += xv * w0.x; acc[1] += xv * w0.y; acc[2] += xv * w0.z; acc[3] += xv * w0.w;
    acc[4] += xv * w1.x; acc[5] += xv * w1.y; acc[6] += xv * w1.z; acc[7] += xv * w1.w;
  }
#pragma unroll
  for (int e = 0; e < NEXP; e++) {
#pragma unroll
    for (int off = 32; off > 0; off >>= 1)
      acc[e] += __shfl_xor(acc[e], off, 64);
  }
  if (lane == 0) {
    float s[NEXP];
#pragma unroll
    for (int e = 0; e < NEXP; e++) s[e] = acc[e] + bg[e];
    int i0 = 0; float b0 = s[0];
#pragma unroll
    for (int e = 1; e < NEXP; e++) if (s[e] > b0) { b0 = s[e]; i0 = e; }
    int i1 = -1; float b1v = -3.4e38f;
#pragma unroll
    for (int e = 0; e < NEXP; e++) if (e != i0 && s[e] > b1v) { b1v = s[e]; i1 = e; }
    float e1 = __expf(b1v - b0);
    float inv = 1.f / (1.f + e1);
    topk_idx[t*2]   = i0;  topk_idx[t*2+1] = i1;
    topk_w[t*2]     = inv; topk_w[t*2+1]   = e1 * inv;
    atomicAdd(&expert_count[i0], 1);
    atomicAdd(&expert_count[i1], 1);
  }
}

// ---------------- scan: offsets + m-tile table ----------------
__global__ void scan_kernel(const int* __restrict__ expert_count,
                            int* __restrict__ expert_offset,
                            int* __restrict__ tile_table,
                            int* __restrict__ num_tiles)
{
  if (threadIdx.x == 0) {
    int off = 0, nt = 0;
    for (int e = 0; e < NEXP; e++) {
      expert_offset[e] = off;
      int c = expert_count[e];
      for (int r = 0; r < c; r += BM) {
        tile_table[nt*4+0] = e;
        tile_table[nt*4+1] = off + r;
        tile_table[nt*4+2] = (c - r) < BM ? (c - r) : BM;
        nt++;
      }
      off += c;
    }
    expert_offset[NEXP] = off;
    *num_tiles = nt;
  }
}

// ---------------- deterministic scatter (ballot ranking) ----------------
__global__ void scatter_kernel(const int* __restrict__ topk_idx,
                               const float* __restrict__ topk_w,
                               const int* __restrict__ expert_offset,
                               int* __restrict__ pair_token,
                               float* __restrict__ pair_w)
{
  const int e = threadIdx.x >> 6;       // 8 waves, one expert each
  const int lane = threadIdx.x & 63;
  int base = expert_offset[e];
  for (int a0 = 0; a0 < N_TOK * KSEL; a0 += 64) {
    int a = a0 + lane;
    int idx = topk_idx[a];
    bool f = (idx == e);
    unsigned long long m = __ballot(f);
    if (f) {
      int pos = base + __popcll(m & ((1ull << lane) - 1ull));
      pair_token[pos] = a >> 1;
      pair_w[pos]     = topk_w[a];
    }
    base += __popcll(m);
  }
}

// ---------------- FFN1: h = relu(x[tok] @ W1[e] + b1[e]) -> bf16 ----------------
__global__ __launch_bounds__(256) void ffn1_kernel(
    const float* __restrict__ x, const float* __restrict__ W1,
    const float* __restrict__ b1, const int* __restrict__ pair_token,
    const int* __restrict__ tile_table, const int* __restrict__ num_tiles,
    unsigned short* __restrict__ h_buf)
{
  const int mt = blockIdx.x;
  if (mt >= *num_tiles) return;
  const int e          = tile_table[mt*4+0];
  const int row_start  = tile_table[mt*4+1];
  const int rows_valid = tile_table[mt*4+2];
  const int n0 = blockIdx.y * BN;

  __shared__ __align__(16) unsigned short As[BM][LDK];
  __shared__ __align__(16) unsigned short Bs[BN][LDK];
  __shared__ int tok[BM];

  const int tid = threadIdx.x;
  if (tid < BM) tok[tid] = pair_token[row_start + (tid < rows_valid ? tid : 0)];
  __syncthreads();

  const float* Bbase = W1 + (size_t)e * DIM * HID + n0;

  f32x4 acc[4][4];
#pragma unroll
  for (int m = 0; m < 4; m++)
#pragma unroll
    for (int n = 0; n < 4; n++) acc[m][n] = (f32x4){0.f, 0.f, 0.f, 0.f};

  const int wave = tid >> 6, lane = tid & 63;
  const int wm = (wave >> 1) * 64, wn = (wave & 1) * 64;
  const int frow = lane & 15;
  const int kb = (lane >> 4) * 8;

  const int arr = tid >> 3;            // A stage: 32 rows/pass
  const int ac4 = (tid & 7) * 4;
  const int bkk = tid >> 5;            // B stage: 8 k/pass
  const int bc4 = (tid & 31) * 4;

  for (int kt = 0; kt < DIM; kt += BK) {
    // stage A (gathered f32 -> bf16)
#pragma unroll
    for (int p = 0; p < 4; p++) {
      int r = p * 32 + arr;
      const f32x4 v = *reinterpret_cast<const f32x4*>(x + (size_t)tok[r] * DIM + kt + ac4);
      unsigned short u0 = f2bf(v.x), u1 = f2bf(v.y), u2 = f2bf(v.z), u3 = f2bf(v.w);
      unsigned long long pk = (unsigned long long)u0 | ((unsigned long long)u1 << 16)
                            | ((unsigned long long)u2 << 32) | ((unsigned long long)u3 << 48);
      *reinterpret_cast<unsigned long long*>(&As[r][ac4]) = pk;
    }
    // stage B transposed: Bs[col][k]
#pragma unroll
    for (int p = 0; p < 4; p++) {
      int k = p * 8 + bkk;
      const f32x4 v = *reinterpret_cast<const f32x4*>(Bbase + (size_t)(kt + k) * HID + bc4);
      Bs[bc4+0][k] = f2bf(v.x);
      Bs[bc4+1][k] = f2bf(v.y);
      Bs[bc4+2][k] = f2bf(v.z);
      Bs[bc4+3][k] = f2bf(v.w);
    }
    __syncthreads();
    bf16x8 af[4], bfr[4];
#pragma unroll
    for (int m = 0; m < 4; m++)
      af[m] = *reinterpret_cast<const bf16x8*>(&As[wm + m*16 + frow][kb]);
#pragma unroll
    for (int n = 0; n < 4; n++)
      bfr[n] = *reinterpret_cast<const bf16x8*>(&Bs[wn + n*16 + frow][kb]);
#pragma unroll
    for (int m = 0; m < 4; m++)
#pragma unroll
      for (int n = 0; n < 4; n++)
        acc[m][n] = __builtin_amdgcn_mfma_f32_16x16x32_bf16(af[m], bfr[n], acc[m][n], 0, 0, 0);
    __syncthreads();
  }

  const int crow = (lane >> 4) * 4;
  const int ccol = lane & 15;
#pragma unroll
  for (int n = 0; n < 4; n++) {
    const int col_g = n0 + wn + n*16 + ccol;
    const float bias = b1[(size_t)e * HID + col_g];
#pragma unroll
    for (int m = 0; m < 4; m++) {
#pragma unroll
      for (int j = 0; j < 4; j++) {
        int r = wm + m*16 + crow + j;
        if (r < rows_valid) {
          float v = acc[m][n][j] + bias;
          h_buf[(size_t)(row_start + r) * HID + col_g] = f2bf(fmaxf(v, 0.f));
        }
      }
    }
  }
}

// ---------------- FFN2: out[t] += w * (h @ W2[e] + b2[e]) ----------------
__global__ __launch_bounds__(256) void ffn2_kernel(
    const unsigned short* __restrict__ h_buf, const float* __restrict__ W2,
    const float* __restrict__ b2, const int* __restrict__ pair_token,
    const float* __restrict__ pair_w, const int* __restrict__ tile_table,
    const int* __restrict__ num_tiles, float* __restrict__ out)
{
  const int mt = blockIdx.x;
  if (mt >= *num_tiles) return;
  const int e          = tile_table[mt*4+0];
  const int row_start  = tile_table[mt*4+1];
  const int rows_valid = tile_table[mt*4+2];
  const int n0 = blockIdx.y * BN;

  __shared__ __align__(16) unsigned short As[BM][LDK];
  __shared__ __align__(16) unsigned short Bs[BN][LDK];
  __shared__ int srow[BM];

  const int tid = threadIdx.x;
  if (tid < BM) srow[tid] = row_start + (tid < rows_valid ? tid : 0);
  __syncthreads();

  const float* Bbase = W2 + (size_t)e * HID * DIM + n0;

  f32x4 acc[4][4];
#pragma unroll
  for (int m = 0; m < 4; m++)
#pragma unroll
    for (int n = 0; n < 4; n++) acc[m][n] = (f32x4){0.f, 0.f, 0.f, 0.f};

  const int wave = tid >> 6, lane = tid & 63;
  const int wm = (wave >> 1) * 64, wn = (wave & 1) * 64;
  const int frow = lane & 15;
  const int kb = (lane >> 4) * 8;

  const int arr = tid >> 2;            // A stage: 64 rows/pass (bf16 x8 loads)
  const int ac8 = (tid & 3) * 8;
  const int bkk = tid >> 5;
  const int bc4 = (tid & 31) * 4;

  for (int kt = 0; kt < HID; kt += BK) {
    // stage A (bf16 direct, 16B per thread per pass)
#pragma unroll
    for (int p = 0; p < 2; p++) {
      int r = p * 64 + arr;
      const f32x4 v = *reinterpret_cast<const f32x4*>(h_buf + (size_t)srow[r] * HID + kt + ac8);
      *reinterpret_cast<f32x4*>(&As[r][ac8]) = v;
    }
    // stage B transposed
#pragma unroll
    for (int p = 0; p < 4; p++) {
      int k = p * 8 + bkk;
      const f32x4 v = *reinterpret_cast<const f32x4*>(Bbase + (size_t)(kt + k) * DIM + bc4);
      Bs[bc4+0][k] = f2bf(v.x);
      Bs[bc4+1][k] = f2bf(v.y);
      Bs[bc4+2][k] = f2bf(v.z);
      Bs[bc4+3][k] = f2bf(v.w);
    }
    __syncthreads();
    bf16x8 af[4], bfr[4];
#pragma unroll
    for (int m = 0; m < 4; m++)
      af[m] = *reinterpret_cast<const bf16x8*>(&As[wm + m*16 + frow][kb]);
#pragma unroll
    for (int n = 0; n < 4; n++)
      bfr[n] = *reinterpret_cast<const bf16x8*>(&Bs[wn + n*16 + frow][kb]);
#pragma unroll
    for (int m = 0; m < 4; m++)
#pragma unroll
      for (int n = 0; n < 4; n++)
        acc[m][n] = __builtin_amdgcn_mfma_f32_16x16x32_bf16(af[m], bfr[n], acc[m][n], 0, 0, 0);
    __syncthreads();
  }

  const int crow = (lane >> 4) * 4;
  const int ccol = lane & 15;
  float bias[4];
#pragma unroll
  for (int n = 0; n < 4; n++) bias[n] = b2[(size_t)e * DIM + n0 + wn + n*16 + ccol];

#pragma unroll
  for (int m = 0; m < 4; m++) {
#pragma unroll
    for (int j = 0; j < 4; j++) {
      int r = wm + m*16 + crow + j;
      if (r < rows_valid) {
        int pos = row_start + r;
        int t = pair_token[pos];
        float w = pair_w[pos];
#pragma unroll
        for (int n = 0; n < 4; n++) {
          int col_g = n0 + wn + n*16 + ccol;
          atomicAdd(&out[(size_t)t * DIM + col_g], (acc[m][n][j] + bias[n]) * w);
        }
      }
    }
  }
}

extern "C" void kernel_launch(void* const* d_in, const int* in_sizes, int n_in,
                              void* d_out, int out_size, void* d_ws, size_t ws_size,
                              hipStream_t stream) {
  const float* x  = (const float*)d_in[0];
  const float* Wg = (const float*)d_in[1];
  const float* bg = (const float*)d_in[2];
  const float* W1 = (const float*)d_in[3];
  const float* b1 = (const float*)d_in[4];
  const float* W2 = (const float*)d_in[5];
  const float* b2 = (const float*)d_in[6];
  float* out = (float*)d_out;

  char* ws = (char*)d_ws;
  int*   expert_count  = (int*)(ws + 0);       // 8 ints
  int*   num_tiles     = (int*)(ws + 64);      // 1 int
  int*   expert_offset = (int*)(ws + 128);     // 9 ints
  int*   tile_table    = (int*)(ws + 256);     // 72*4 ints
  int*   topk_idx      = (int*)(ws + 4096);                // 32KB
  float* topk_w        = (float*)(ws + 4096 + 32768);      // 32KB
  int*   pair_token    = (int*)(ws + 4096 + 65536);        // 32KB
  float* pair_w        = (float*)(ws + 4096 + 98304);      // 32KB
  unsigned short* h_buf = (unsigned short*)(ws + 135168);  // 8192*4096*2 = 64MiB

  hipMemsetAsync(ws, 0, 256, stream);
  hipMemsetAsync(d_out, 0, (size_t)N_TOK * DIM * sizeof(float), stream);

  gate_kernel<<<N_TOK / 4, 256, 0, stream>>>(x, Wg, bg, topk_idx, topk_w, expert_count);
  scan_kernel<<<1, 64, 0, stream>>>(expert_count, expert_offset, tile_table, num_tiles);
  scatter_kernel<<<1, 512, 0, stream>>>(topk_idx, topk_w, expert_offset, pair_token, pair_w);
  ffn1_kernel<<<dim3(MAXT, HID / BN), 256, 0, stream>>>(x, W1, b1, pair_token, tile_table,
                                                        num_tiles, h_buf);
  ffn2_kernel<<<dim3(MAXT, DIM / BN), 256, 0, stream>>>(h_buf, W2, b2, pair_token, pair_w,
                                                        tile_table, num_tiles, out);
}

// Round 2
// 530.090 us; speedup vs baseline: 1.8879x; 1.8879x over previous
//
#include <hip/hip_runtime.h>
#include <hip/hip_bf16.h>

#define N_TOK 4096
#define DIM   1024
#define HID   4096
#define NEXP  8
#define KSEL  2
#define NPOS  (N_TOK * KSEL)   // 8192 total expert-token pairs

#define BM 128
#define BN 128
#define BK 32
#define MAXT 72   // max m-tiles: 8192/128 + 8 expert-boundary tiles

typedef float  f32x4  __attribute__((ext_vector_type(4)));
typedef __bf16 bf16x8 __attribute__((ext_vector_type(8)));
typedef unsigned short us8 __attribute__((ext_vector_type(8)));

__device__ __forceinline__ unsigned short f2bf(float f) {
  __hip_bfloat16 h = __float2bfloat16(f);
  return *reinterpret_cast<unsigned short*>(&h);
}
__device__ __forceinline__ float bf2f(unsigned short u) {
  unsigned int x = ((unsigned int)u) << 16;
  return __builtin_bit_cast(float, x);
}

// async global->LDS, 16B per lane. LDS dest must be wave-uniform base (lane*16 implicit).
__device__ __forceinline__ void gload16(const void* g, void* l) {
  __builtin_amdgcn_global_load_lds(
      (const __attribute__((address_space(1))) unsigned int*)g,
      (__attribute__((address_space(3))) unsigned int*)l, 16, 0, 0);
}

// ---------------- gating: scores, top-2, softmax ----------------
__global__ __launch_bounds__(256) void gate_kernel(
    const float* __restrict__ x, const float* __restrict__ Wg,
    const float* __restrict__ bg, int* __restrict__ topk_idx,
    float* __restrict__ topk_w, int* __restrict__ expert_count)
{
  const int wave = threadIdx.x >> 6, lane = threadIdx.x & 63;
  const int t = blockIdx.x * 4 + wave;
  const float* xr = x + (size_t)t * DIM;

  float acc[NEXP];
#pragma unroll
  for (int e = 0; e < NEXP; e++) acc[e] = 0.f;

  for (int d = lane; d < DIM; d += 64) {
    float xv = xr[d];
    const f32x4* wr = reinterpret_cast<const f32x4*>(Wg + (size_t)d * NEXP);
    f32x4 w0 = wr[0], w1 = wr[1];
    acc[0] += xv * w0.x; acc[1] += xv * w0.y; acc[2] += xv * w0.z; acc[3] += xv * w0.w;
    acc[4] += xv * w1.x; acc[5] += xv * w1.y; acc[6] += xv * w1.z; acc[7] += xv * w1.w;
  }
#pragma unroll
  for (int e = 0; e < NEXP; e++) {
#pragma unroll
    for (int off = 32; off > 0; off >>= 1)
      acc[e] += __shfl_xor(acc[e], off, 64);
  }
  if (lane == 0) {
    float s[NEXP];
#pragma unroll
    for (int e = 0; e < NEXP; e++) s[e] = acc[e] + bg[e];
    int i0 = 0; float b0 = s[0];
#pragma unroll
    for (int e = 1; e < NEXP; e++) if (s[e] > b0) { b0 = s[e]; i0 = e; }
    int i1 = -1; float b1v = -3.4e38f;
#pragma unroll
    for (int e = 0; e < NEXP; e++) if (e != i0 && s[e] > b1v) { b1v = s[e]; i1 = e; }
    float e1 = __expf(b1v - b0);
    float inv = 1.f / (1.f + e1);
    topk_idx[t*2]   = i0;  topk_idx[t*2+1] = i1;
    topk_w[t*2]     = inv; topk_w[t*2+1]   = e1 * inv;
    atomicAdd(&expert_count[i0], 1);
    atomicAdd(&expert_count[i1], 1);
  }
}

// ---------------- scan: offsets + m-tile table ----------------
__global__ void scan_kernel(const int* __restrict__ expert_count,
                            int* __restrict__ expert_offset,
                            int* __restrict__ tile_table,
                            int* __restrict__ num_tiles)
{
  if (threadIdx.x == 0) {
    int off = 0, nt = 0;
    for (int e = 0; e < NEXP; e++) {
      expert_offset[e] = off;
      int c = expert_count[e];
      for (int r = 0; r < c; r += BM) {
        tile_table[nt*4+0] = e;
        tile_table[nt*4+1] = off + r;
        tile_table[nt*4+2] = (c - r) < BM ? (c - r) : BM;
        nt++;
      }
      off += c;
    }
    expert_offset[NEXP] = off;
    *num_tiles = nt;
  }
}

// ---------------- deterministic scatter (ballot ranking) ----------------
__global__ void scatter_kernel(const int* __restrict__ topk_idx,
                               const float* __restrict__ topk_w,
                               const int* __restrict__ expert_offset,
                               int* __restrict__ pair_token,
                               float* __restrict__ pair_w,
                               int* __restrict__ pos_of)
{
  const int e = threadIdx.x >> 6;       // 8 waves, one expert each
  const int lane = threadIdx.x & 63;
  int base = expert_offset[e];
  for (int a0 = 0; a0 < NPOS; a0 += 64) {
    int a = a0 + lane;
    int idx = topk_idx[a];
    bool f = (idx == e);
    unsigned long long m = __ballot(f);
    if (f) {
      int pos = base + __popcll(m & ((1ull << lane) - 1ull));
      pair_token[pos] = a >> 1;
      pair_w[pos]     = topk_w[a];
      pos_of[a]       = pos;
    }
    base += __popcll(m);
  }
}

// ---------------- x: f32 -> bf16 ----------------
__global__ __launch_bounds__(256) void xconv_kernel(const float* __restrict__ x,
                                                    unsigned short* __restrict__ xb)
{
  int i = blockIdx.x * 256 + threadIdx.x;   // covers 4 elements each
  f32x4 v = *reinterpret_cast<const f32x4*>(x + (size_t)i * 4);
  unsigned long long pk = (unsigned long long)f2bf(v.x)
                        | ((unsigned long long)f2bf(v.y) << 16)
                        | ((unsigned long long)f2bf(v.z) << 32)
                        | ((unsigned long long)f2bf(v.w) << 48);
  *reinterpret_cast<unsigned long long*>(xb + (size_t)i * 4) = pk;
}

// ---------------- weight transpose+convert: src [E][R][C] f32 -> dst [E][C][R] bf16 ----
__global__ __launch_bounds__(256) void transpose_kernel(const float* __restrict__ src,
                                                        unsigned short* __restrict__ dst,
                                                        int R, int C)
{
  __shared__ float S[64][67];   // odd stride: scalar column reads ~2-way (free)
  const int e = blockIdx.z;
  const float* s = src + (size_t)e * R * C;
  unsigned short* d = dst + (size_t)e * R * C;
  const int r0 = blockIdx.y * 64, c0 = blockIdx.x * 64;
  const int tid = threadIdx.x;

  // read phase: 64 rows x 64 cols f32, coalesced
  {
    const int rr = tid >> 2, cc = (tid & 3) * 16;
    const float* sp = s + (size_t)(r0 + rr) * C + c0 + cc;
#pragma unroll
    for (int j = 0; j < 4; j++) {
      f32x4 v = *reinterpret_cast<const f32x4*>(sp + j * 4);
      S[rr][cc + j*4 + 0] = v.x;
      S[rr][cc + j*4 + 1] = v.y;
      S[rr][cc + j*4 + 2] = v.z;
      S[rr][cc + j*4 + 3] = v.w;
    }
  }
  __syncthreads();
  // write phase: out row = src col; coalesced bf16x8 stores
  {
    const int hh = tid >> 2, dbase = (tid & 3) * 16;
    us8 o0, o1;
#pragma unroll
    for (int i = 0; i < 8; i++) o0[i] = f2bf(S[dbase + i][hh]);
#pragma unroll
    for (int i = 0; i < 8; i++) o1[i] = f2bf(S[dbase + 8 + i][hh]);
    unsigned short* dp = d + (size_t)(c0 + hh) * R + r0 + dbase;
    *reinterpret_cast<us8*>(dp)     = o0;
    *reinterpret_cast<us8*>(dp + 8) = o1;
  }
}

// ---------------- FFN1: h = relu(xb[tok] @ Wt1[e]^T + b1[e]) -> bf16 ----------------
// Wt1 is [E][HID][DIM] bf16 (N-major / B^T layout)
__global__ __launch_bounds__(256) void ffn1_kernel(
    const unsigned short* __restrict__ xb, const unsigned short* __restrict__ Wt1,
    const float* __restrict__ b1, const int* __restrict__ pair_token,
    const int* __restrict__ tile_table, const int* __restrict__ num_tiles,
    unsigned short* __restrict__ h_buf)
{
  const int mt = blockIdx.x;
  if (mt >= *num_tiles) return;
  const int e          = tile_table[mt*4+0];
  const int row_start  = tile_table[mt*4+1];
  const int rows_valid = tile_table[mt*4+2];
  const int n0 = blockIdx.y * BN;

  __shared__ __align__(16) unsigned short As[BM][BK];
  __shared__ __align__(16) unsigned short Bs[BN][BK];
  __shared__ int tok[BM];

  const int tid = threadIdx.x;
  if (tid < BM) tok[tid] = pair_token[row_start + (tid < rows_valid ? tid : 0)];
  __syncthreads();

  const int w = tid >> 6, l = tid & 63;
  const int colo = (l & 3) * 8;            // bf16 element offset within a 32-elem row
  const int r0 = w * 16 + (l >> 2);        // issue p=0 row
  const int r1 = 64 + r0;                  // issue p=1 row

  const unsigned short* gA0 = xb + (size_t)tok[r0] * DIM + colo;
  const unsigned short* gA1 = xb + (size_t)tok[r1] * DIM + colo;
  const unsigned short* We  = Wt1 + (size_t)e * HID * DIM;
  const unsigned short* gB0 = We + (size_t)(n0 + r0) * DIM + colo;
  const unsigned short* gB1 = We + (size_t)(n0 + r1) * DIM + colo;
  char* ldsA0 = (char*)&As[0][0] + w * 1024;
  char* ldsA1 = ldsA0 + 4096;
  char* ldsB0 = (char*)&Bs[0][0] + w * 1024;
  char* ldsB1 = ldsB0 + 4096;

  f32x4 acc[4][4];
#pragma unroll
  for (int m = 0; m < 4; m++)
#pragma unroll
    for (int n = 0; n < 4; n++) acc[m][n] = (f32x4){0.f, 0.f, 0.f, 0.f};

  const int wm = (w >> 1) * 64, wn = (w & 1) * 64;
  const int frow = l & 15, kb = (l >> 4) * 8;

  for (int kt = 0; kt < DIM; kt += BK) {
    gload16(gA0 + kt, ldsA0);
    gload16(gA1 + kt, ldsA1);
    gload16(gB0 + kt, ldsB0);
    gload16(gB1 + kt, ldsB1);
    __syncthreads();   // drains vmcnt -> LDS tiles ready
    bf16x8 af[4], bfr[4];
#pragma unroll
    for (int m = 0; m < 4; m++)
      af[m] = *reinterpret_cast<const bf16x8*>(&As[wm + m*16 + frow][kb]);
#pragma unroll
    for (int n = 0; n < 4; n++)
      bfr[n] = *reinterpret_cast<const bf16x8*>(&Bs[wn + n*16 + frow][kb]);
#pragma unroll
    for (int m = 0; m < 4; m++)
#pragma unroll
      for (int n = 0; n < 4; n++)
        acc[m][n] = __builtin_amdgcn_mfma_f32_16x16x32_bf16(af[m], bfr[n], acc[m][n], 0, 0, 0);
    __syncthreads();
  }

  const int crow = (l >> 4) * 4;
  const int ccol = l & 15;
#pragma unroll
  for (int n = 0; n < 4; n++) {
    const int cg = n0 + wn + n*16 + ccol;
    const float bias = b1[(size_t)e * HID + cg];
#pragma unroll
    for (int m = 0; m < 4; m++) {
#pragma unroll
      for (int j = 0; j < 4; j++) {
        int r = wm + m*16 + crow + j;
        if (r < rows_valid)
          h_buf[(size_t)(row_start + r) * HID + cg] = f2bf(fmaxf(acc[m][n][j] + bias, 0.f));
      }
    }
  }
}

// ---------------- FFN2: y[pos] = w[pos] * (h[pos] @ Wt2[e]^T + b2[e]) -> bf16 --------
// Wt2 is [E][DIM][HID] bf16 (N-major / B^T layout); h rows are contiguous positions
__global__ __launch_bounds__(256) void ffn2_kernel(
    const unsigned short* __restrict__ h_buf, const unsigned short* __restrict__ Wt2,
    const float* __restrict__ b2, const float* __restrict__ pair_w,
    const int* __restrict__ tile_table, const int* __restrict__ num_tiles,
    unsigned short* __restrict__ y)
{
  const int mt = blockIdx.x;
  if (mt >= *num_tiles) return;
  const int e          = tile_table[mt*4+0];
  const int row_start  = tile_table[mt*4+1];
  const int rows_valid = tile_table[mt*4+2];
  const int n0 = blockIdx.y * BN;

  __shared__ __align__(16) unsigned short As[BM][BK];
  __shared__ __align__(16) unsigned short Bs[BN][BK];

  const int tid = threadIdx.x;
  const int w = tid >> 6, l = tid & 63;
  const int colo = (l & 3) * 8;
  const int r0 = w * 16 + (l >> 2);
  const int r1 = 64 + r0;
  int ar0 = row_start + r0; if (ar0 > NPOS - 1) ar0 = NPOS - 1;  // clamp padding reads
  int ar1 = row_start + r1; if (ar1 > NPOS - 1) ar1 = NPOS - 1;

  const unsigned short* gA0 = h_buf + (size_t)ar0 * HID + colo;
  const unsigned short* gA1 = h_buf + (size_t)ar1 * HID + colo;
  const unsigned short* We  = Wt2 + (size_t)e * DIM * HID;
  const unsigned short* gB0 = We + (size_t)(n0 + r0) * HID + colo;
  const unsigned short* gB1 = We + (size_t)(n0 + r1) * HID + colo;
  char* ldsA0 = (char*)&As[0][0] + w * 1024;
  char* ldsA1 = ldsA0 + 4096;
  char* ldsB0 = (char*)&Bs[0][0] + w * 1024;
  char* ldsB1 = ldsB0 + 4096;

  f32x4 acc[4][4];
#pragma unroll
  for (int m = 0; m < 4; m++)
#pragma unroll
    for (int n = 0; n < 4; n++) acc[m][n] = (f32x4){0.f, 0.f, 0.f, 0.f};

  const int wm = (w >> 1) * 64, wn = (w & 1) * 64;
  const int frow = l & 15, kb = (l >> 4) * 8;

  for (int kt = 0; kt < HID; kt += BK) {
    gload16(gA0 + kt, ldsA0);
    gload16(gA1 + kt, ldsA1);
    gload16(gB0 + kt, ldsB0);
    gload16(gB1 + kt, ldsB1);
    __syncthreads();
    bf16x8 af[4], bfr[4];
#pragma unroll
    for (int m = 0; m < 4; m++)
      af[m] = *reinterpret_cast<const bf16x8*>(&As[wm + m*16 + frow][kb]);
#pragma unroll
    for (int n = 0; n < 4; n++)
      bfr[n] = *reinterpret_cast<const bf16x8*>(&Bs[wn + n*16 + frow][kb]);
#pragma unroll
    for (int m = 0; m < 4; m++)
#pragma unroll
      for (int n = 0; n < 4; n++)
        acc[m][n] = __builtin_amdgcn_mfma_f32_16x16x32_bf16(af[m], bfr[n], acc[m][n], 0, 0, 0);
    __syncthreads();
  }

  const int crow = (l >> 4) * 4;
  const int ccol = l & 15;
  float bias[4];
#pragma unroll
  for (int n = 0; n < 4; n++) bias[n] = b2[(size_t)e * DIM + n0 + wn + n*16 + ccol];

#pragma unroll
  for (int m = 0; m < 4; m++) {
#pragma unroll
    for (int j = 0; j < 4; j++) {
      int r = wm + m*16 + crow + j;
      if (r < rows_valid) {
        int pos = row_start + r;
        float wv = pair_w[pos];
#pragma unroll
        for (int n = 0; n < 4; n++)
          y[(size_t)pos * DIM + n0 + wn + n*16 + ccol] = f2bf((acc[m][n][j] + bias[n]) * wv);
      }
    }
  }
}

// ---------------- combine: out[t] = y[pos(t,0)] + y[pos(t,1)] ----------------
__global__ __launch_bounds__(256) void combine_kernel(const unsigned short* __restrict__ y,
                                                      const int* __restrict__ pos_of,
                                                      float* __restrict__ out)
{
  const int t = blockIdx.x * 4 + (threadIdx.x >> 6);
  const int lane = threadIdx.x & 63;
  const int p0 = pos_of[2*t], p1 = pos_of[2*t+1];
  const unsigned short* a = y + (size_t)p0 * DIM;
  const unsigned short* b = y + (size_t)p1 * DIM;
  float* o = out + (size_t)t * DIM;
#pragma unroll
  for (int i = 0; i < 4; i++) {
    int d = i * 256 + lane * 4;
    unsigned long long va = *reinterpret_cast<const unsigned long long*>(a + d);
    unsigned long long vb = *reinterpret_cast<const unsigned long long*>(b + d);
    f32x4 r;
#pragma unroll
    for (int k = 0; k < 4; k++)
      r[k] = bf2f((unsigned short)(va >> (16*k))) + bf2f((unsigned short)(vb >> (16*k)));
    *reinterpret_cast<f32x4*>(o + d) = r;
  }
}

extern "C" void kernel_launch(void* const* d_in, const int* in_sizes, int n_in,
                              void* d_out, int out_size, void* d_ws, size_t ws_size,
                              hipStream_t stream) {
  const float* x  = (const float*)d_in[0];
  const float* Wg = (const float*)d_in[1];
  const float* bg = (const float*)d_in[2];
  const float* W1 = (const float*)d_in[3];
  const float* b1 = (const float*)d_in[4];
  const float* W2 = (const float*)d_in[5];
  const float* b2 = (const float*)d_in[6];
  float* out = (float*)d_out;

  char* ws = (char*)d_ws;
  const size_t MB = 1024 * 1024;
  int*   expert_count  = (int*)(ws + 0);
  int*   num_tiles     = (int*)(ws + 64);
  int*   expert_offset = (int*)(ws + 128);
  int*   tile_table    = (int*)(ws + 256);
  int*   topk_idx      = (int*)(ws + 4096);
  float* topk_w        = (float*)(ws + 4096 + 32768);
  int*   pair_token    = (int*)(ws + 4096 + 65536);
  float* pair_w        = (float*)(ws + 4096 + 98304);
  int*   pos_of        = (int*)(ws + 4096 + 131072);
  unsigned short* xb   = (unsigned short*)(ws + 1*MB);    //  8 MiB  [4096][1024] bf16
  unsigned short* y    = (unsigned short*)(ws + 9*MB);    // 16 MiB  [8192][1024] bf16
  unsigned short* Wt   = (unsigned short*)(ws + 25*MB);   // 64 MiB  (Wt1, then Wt2)
  unsigned short* h    = (unsigned short*)(ws + 89*MB);   // 64 MiB  [8192][4096] bf16
                                                          // total: 153 MiB

  hipMemsetAsync(ws, 0, 256, stream);

  gate_kernel<<<N_TOK / 4, 256, 0, stream>>>(x, Wg, bg, topk_idx, topk_w, expert_count);
  scan_kernel<<<1, 64, 0, stream>>>(expert_count, expert_offset, tile_table, num_tiles);
  scatter_kernel<<<1, 512, 0, stream>>>(topk_idx, topk_w, expert_offset,
                                        pair_token, pair_w, pos_of);
  xconv_kernel<<<(N_TOK * DIM) / (256 * 4), 256, 0, stream>>>(x, xb);
  // Wt1 = W1^T per expert: [D][H] -> [H][D]
  transpose_kernel<<<dim3(HID/64, DIM/64, NEXP), 256, 0, stream>>>(W1, Wt, DIM, HID);
  ffn1_kernel<<<dim3(MAXT, HID / BN), 256, 0, stream>>>(xb, Wt, b1, pair_token,
                                                        tile_table, num_tiles, h);
  // Wt2 = W2^T per expert: [H][D] -> [D][H]  (reuses Wt buffer)
  transpose_kernel<<<dim3(DIM/64, HID/64, NEXP), 256, 0, stream>>>(W2, Wt, HID, DIM);
  ffn2_kernel<<<dim3(MAXT, DIM / BN), 256, 0, stream>>>(h, Wt, b2, pair_w,
                                                        tile_table, num_tiles, y);
  combine_kernel<<<N_TOK / 4, 256, 0, stream>>>(y, pos_of, out);
}

// Round 3
// 513.818 us; speedup vs baseline: 1.9477x; 1.0317x over previous
//
#include <hip/hip_runtime.h>
#include <hip/hip_bf16.h>

#define N_TOK 4096
#define DIM   1024
#define HID   4096
#define NEXP  8
#define KSEL  2
#define NPOS  (N_TOK * KSEL)   // 8192 expert-token pairs

#define BK 32
#define MAXT1 40   // ffn1 m-tiles (BM=256): 8192/256 + 8
#define MAXT2 72   // ffn2 m-tiles (BM=128): 8192/128 + 8

typedef float  f32x4  __attribute__((ext_vector_type(4)));
typedef __bf16 bf16x8 __attribute__((ext_vector_type(8)));
typedef unsigned short us8 __attribute__((ext_vector_type(8)));

__device__ __forceinline__ unsigned short f2bf(float f) {
  __hip_bfloat16 h = __float2bfloat16(f);
  return *reinterpret_cast<unsigned short*>(&h);
}
__device__ __forceinline__ float bf2f(unsigned short u) {
  unsigned int x = ((unsigned int)u) << 16;
  return __builtin_bit_cast(float, x);
}
__device__ __forceinline__ void gload16(const void* g, void* l) {
  __builtin_amdgcn_global_load_lds(
      (const __attribute__((address_space(1))) unsigned int*)g,
      (__attribute__((address_space(3))) unsigned int*)l, 16, 0, 0);
}
#define BAR()    __builtin_amdgcn_s_barrier()
#define WAITV(n) asm volatile("s_waitcnt vmcnt(" #n ")" ::: "memory")
#define WAITL()  asm volatile("s_waitcnt lgkmcnt(0)" ::: "memory")

// ---------------- gating ----------------
__global__ __launch_bounds__(256) void gate_kernel(
    const float* __restrict__ x, const float* __restrict__ Wg,
    const float* __restrict__ bg, int* __restrict__ topk_idx,
    float* __restrict__ topk_w, int* __restrict__ expert_count)
{
  const int wave = threadIdx.x >> 6, lane = threadIdx.x & 63;
  const int t = blockIdx.x * 4 + wave;
  const float* xr = x + (size_t)t * DIM;

  float acc[NEXP];
#pragma unroll
  for (int e = 0; e < NEXP; e++) acc[e] = 0.f;
  for (int d = lane; d < DIM; d += 64) {
    float xv = xr[d];
    const f32x4* wr = reinterpret_cast<const f32x4*>(Wg + (size_t)d * NEXP);
    f32x4 w0 = wr[0], w1 = wr[1];
    acc[0] += xv * w0.x; acc[1] += xv * w0.y; acc[2] += xv * w0.z; acc[3] += xv * w0.w;
    acc[4] += xv * w1.x; acc[5] += xv * w1.y; acc[6] += xv * w1.z; acc[7] += xv * w1.w;
  }
#pragma unroll
  for (int e = 0; e < NEXP; e++) {
#pragma unroll
    for (int off = 32; off > 0; off >>= 1)
      acc[e] += __shfl_xor(acc[e], off, 64);
  }
  if (lane == 0) {
    float s[NEXP];
#pragma unroll
    for (int e = 0; e < NEXP; e++) s[e] = acc[e] + bg[e];
    int i0 = 0; float b0 = s[0];
#pragma unroll
    for (int e = 1; e < NEXP; e++) if (s[e] > b0) { b0 = s[e]; i0 = e; }
    int i1 = -1; float b1v = -3.4e38f;
#pragma unroll
    for (int e = 0; e < NEXP; e++) if (e != i0 && s[e] > b1v) { b1v = s[e]; i1 = e; }
    float e1 = __expf(b1v - b0);
    float inv = 1.f / (1.f + e1);
    topk_idx[t*2]   = i0;  topk_idx[t*2+1] = i1;
    topk_w[t*2]     = inv; topk_w[t*2+1]   = e1 * inv;
    atomicAdd(&expert_count[i0], 1);
    atomicAdd(&expert_count[i1], 1);
  }
}

// ---------------- scan: offsets + two m-tile tables (BM=256 and BM=128) --------
__global__ void scan_kernel(const int* __restrict__ expert_count,
                            int* __restrict__ expert_offset,
                            int* __restrict__ table1, int* __restrict__ nt1,
                            int* __restrict__ table2, int* __restrict__ nt2)
{
  if (threadIdx.x == 0) {
    int off = 0, a = 0, b = 0;
    for (int e = 0; e < NEXP; e++) {
      expert_offset[e] = off;
      int c = expert_count[e];
      for (int r = 0; r < c; r += 256) {
        table1[a*4+0] = e; table1[a*4+1] = off + r;
        table1[a*4+2] = (c - r) < 256 ? (c - r) : 256; a++;
      }
      for (int r = 0; r < c; r += 128) {
        table2[b*4+0] = e; table2[b*4+1] = off + r;
        table2[b*4+2] = (c - r) < 128 ? (c - r) : 128; b++;
      }
      off += c;
    }
    expert_offset[NEXP] = off;
    *nt1 = a; *nt2 = b;
  }
}

// ---------------- deterministic scatter ----------------
__global__ void scatter_kernel(const int* __restrict__ topk_idx,
                               const float* __restrict__ topk_w,
                               const int* __restrict__ expert_offset,
                               int* __restrict__ pair_token,
                               float* __restrict__ pair_w,
                               int* __restrict__ pos_of)
{
  const int e = threadIdx.x >> 6;
  const int lane = threadIdx.x & 63;
  int base = expert_offset[e];
  for (int a0 = 0; a0 < NPOS; a0 += 64) {
    int a = a0 + lane;
    int idx = topk_idx[a];
    bool f = (idx == e);
    unsigned long long m = __ballot(f);
    if (f) {
      int pos = base + __popcll(m & ((1ull << lane) - 1ull));
      pair_token[pos] = a >> 1;
      pair_w[pos]     = topk_w[a];
      pos_of[a]       = pos;
    }
    base += __popcll(m);
  }
}

// ---------------- x: f32 -> bf16 ----------------
__global__ __launch_bounds__(256) void xconv_kernel(const float* __restrict__ x,
                                                    unsigned short* __restrict__ xb)
{
  int i = blockIdx.x * 256 + threadIdx.x;
  f32x4 v = *reinterpret_cast<const f32x4*>(x + (size_t)i * 4);
  unsigned long long pk = (unsigned long long)f2bf(v.x)
                        | ((unsigned long long)f2bf(v.y) << 16)
                        | ((unsigned long long)f2bf(v.z) << 32)
                        | ((unsigned long long)f2bf(v.w) << 48);
  *reinterpret_cast<unsigned long long*>(xb + (size_t)i * 4) = pk;
}

// ---------------- weight transpose+convert [E][R][C] f32 -> [E][C][R] bf16 ------
__global__ __launch_bounds__(256) void transpose_kernel(const float* __restrict__ src,
                                                        unsigned short* __restrict__ dst,
                                                        int R, int C)
{
  __shared__ float S[64][67];
  const int e = blockIdx.z;
  const float* s = src + (size_t)e * R * C;
  unsigned short* d = dst + (size_t)e * R * C;
  const int r0 = blockIdx.y * 64, c0 = blockIdx.x * 64;
  const int tid = threadIdx.x;
  {
    const int rr = tid >> 2, cc = (tid & 3) * 16;
    const float* sp = s + (size_t)(r0 + rr) * C + c0 + cc;
#pragma unroll
    for (int j = 0; j < 4; j++) {
      f32x4 v = *reinterpret_cast<const f32x4*>(sp + j * 4);
      S[rr][cc + j*4 + 0] = v.x;
      S[rr][cc + j*4 + 1] = v.y;
      S[rr][cc + j*4 + 2] = v.z;
      S[rr][cc + j*4 + 3] = v.w;
    }
  }
  __syncthreads();
  {
    const int hh = tid >> 2, dbase = (tid & 3) * 16;
    us8 o0, o1;
#pragma unroll
    for (int i = 0; i < 8; i++) o0[i] = f2bf(S[dbase + i][hh]);
#pragma unroll
    for (int i = 0; i < 8; i++) o1[i] = f2bf(S[dbase + 8 + i][hh]);
    unsigned short* dp = d + (size_t)(c0 + hh) * R + r0 + dbase;
    *reinterpret_cast<us8*>(dp)     = o0;
    *reinterpret_cast<us8*>(dp + 8) = o1;
  }
}

// ---------------- FFN1: BM=256 BN=128 BK=32, 512 thr, 2-phase dbuf pipeline ------
// Wt1 [E][HID][DIM] bf16; out h [NPOS][HID] bf16 (relu'd)
__global__ __launch_bounds__(512) void ffn1_kernel(
    const unsigned short* __restrict__ xb, const unsigned short* __restrict__ Wt1,
    const float* __restrict__ b1, const int* __restrict__ pair_token,
    const int* __restrict__ table1, const int* __restrict__ nt1,
    unsigned short* __restrict__ h_buf)
{
  // XCD-aware swizzle over 1280 wgs (1280 % 8 == 0), then mt-major decompose
  int wg = blockIdx.x;
  wg = (wg & 7) * (MAXT1 * 32 / 8) + (wg >> 3);
  const int mt = wg % MAXT1;
  const int n0 = (wg / MAXT1) * 128;
  if (mt >= *nt1) return;

  const int e          = table1[mt*4+0];
  const int row_start  = table1[mt*4+1];
  const int rows_valid = table1[mt*4+2];

  __shared__ __align__(16) unsigned short As0[256*BK], As1[256*BK];
  __shared__ __align__(16) unsigned short Bs0[128*BK], Bs1[128*BK];
  __shared__ int tok[256];

  const int tid = threadIdx.x;
  if (tid < 256) tok[tid] = pair_token[row_start + (tid < rows_valid ? tid : 0)];
  __syncthreads();

  const int w = tid >> 6, l = tid & 63;
  const int srow = w * 16 + (l >> 2);      // stage row within 128-row round
  const int q8   = (l & 3) * 8;            // 8-elem column offset

  const unsigned short* pA0 = xb + (size_t)tok[srow] * DIM + q8;
  const unsigned short* pA1 = xb + (size_t)tok[128 + srow] * DIM + q8;
  const unsigned short* pB  = Wt1 + (size_t)e * HID * DIM + (size_t)(n0 + srow) * DIM + q8;
  const int ldsOff = w * 1024;

  f32x4 acc[4][4];
#pragma unroll
  for (int m = 0; m < 4; m++)
#pragma unroll
    for (int n = 0; n < 4; n++) acc[m][n] = (f32x4){0.f, 0.f, 0.f, 0.f};

  const int wr = w >> 1, wc = w & 1;
  const int frow = l & 15, kb = (l >> 4) * 8;
  const unsigned short* arow0 = nullptr;  // silence unused warnings pattern

  auto STAGE = [&](int kt, unsigned short* A, unsigned short* B) {
    gload16(pA0 + kt, (char*)A + ldsOff);
    gload16(pA1 + kt, (char*)A + 8192 + ldsOff);
    gload16(pB  + kt, (char*)B + ldsOff);
  };
  auto COMPUTE = [&](const unsigned short* A, const unsigned short* B) {
    bf16x8 af[4], bfr[4];
#pragma unroll
    for (int m = 0; m < 4; m++)
      af[m] = *reinterpret_cast<const bf16x8*>(A + (wr*64 + m*16 + frow) * BK + kb);
#pragma unroll
    for (int n = 0; n < 4; n++)
      bfr[n] = *reinterpret_cast<const bf16x8*>(B + (wc*64 + n*16 + frow) * BK + kb);
#pragma unroll
    for (int m = 0; m < 4; m++)
#pragma unroll
      for (int n = 0; n < 4; n++)
        acc[m][n] = __builtin_amdgcn_mfma_f32_16x16x32_bf16(af[m], bfr[n], acc[m][n], 0, 0, 0);
    WAITL();
    BAR();
  };

  STAGE(0, As0, Bs0);
  int ks = BK;
  // NT = DIM/BK = 32 steps -> 15 double-iterations + tail pair
  for (int i = 0; i < 15; i++) {
    STAGE(ks, As1, Bs1); ks += BK;
    WAITV(3); BAR();
    COMPUTE(As0, Bs0);
    STAGE(ks, As0, Bs0); ks += BK;
    WAITV(3); BAR();
    COMPUTE(As1, Bs1);
  }
  STAGE(ks, As1, Bs1);
  WAITV(3); BAR();
  COMPUTE(As0, Bs0);
  WAITV(0); BAR();
  COMPUTE(As1, Bs1);

  const int crow = (l >> 4) * 4;
  const int ccol = l & 15;
#pragma unroll
  for (int n = 0; n < 4; n++) {
    const int cg = n0 + wc*64 + n*16 + ccol;
    const float bias = b1[(size_t)e * HID + cg];
#pragma unroll
    for (int m = 0; m < 4; m++) {
#pragma unroll
      for (int j = 0; j < 4; j++) {
        int r = wr*64 + m*16 + crow + j;
        if (r < rows_valid)
          h_buf[(size_t)(row_start + r) * HID + cg] = f2bf(fmaxf(acc[m][n][j] + bias, 0.f));
      }
    }
  }
  (void)arow0;
}

// ---------------- FFN2: BM=128 BN=128 BK=32, 256 thr, 2-phase dbuf pipeline ------
// Wt2 [E][DIM][HID] bf16; out y [NPOS][DIM] bf16 (pre-weighted)
__global__ __launch_bounds__(256) void ffn2_kernel(
    const unsigned short* __restrict__ h_buf, const unsigned short* __restrict__ Wt2,
    const float* __restrict__ b2, const float* __restrict__ pair_w,
    const int* __restrict__ table2, const int* __restrict__ nt2,
    unsigned short* __restrict__ y)
{
  int wg = blockIdx.x;                       // 576 wgs, 576 % 8 == 0
  wg = (wg & 7) * (MAXT2 * 8 / 8) + (wg >> 3);
  const int mt = wg % MAXT2;
  const int n0 = (wg / MAXT2) * 128;
  if (mt >= *nt2) return;

  const int e          = table2[mt*4+0];
  const int row_start  = table2[mt*4+1];
  const int rows_valid = table2[mt*4+2];

  __shared__ __align__(16) unsigned short As0[128*BK], As1[128*BK];
  __shared__ __align__(16) unsigned short Bs0[128*BK], Bs1[128*BK];

  const int tid = threadIdx.x;
  const int w = tid >> 6, l = tid & 63;
  const int srow = w * 16 + (l >> 2);        // row within 64-row round
  const int q8   = (l & 3) * 8;

  int ar0 = row_start + srow;       if (ar0 > NPOS - 1) ar0 = NPOS - 1;
  int ar1 = row_start + 64 + srow;  if (ar1 > NPOS - 1) ar1 = NPOS - 1;

  const unsigned short* pA0 = h_buf + (size_t)ar0 * HID + q8;
  const unsigned short* pA1 = h_buf + (size_t)ar1 * HID + q8;
  const unsigned short* We  = Wt2 + (size_t)e * DIM * HID;
  const unsigned short* pB0 = We + (size_t)(n0 + srow) * HID + q8;
  const unsigned short* pB1 = We + (size_t)(n0 + 64 + srow) * HID + q8;
  const int ldsOff = w * 1024;

  f32x4 acc[4][4];
#pragma unroll
  for (int m = 0; m < 4; m++)
#pragma unroll
    for (int n = 0; n < 4; n++) acc[m][n] = (f32x4){0.f, 0.f, 0.f, 0.f};

  const int wr = w >> 1, wc = w & 1;
  const int frow = l & 15, kb = (l >> 4) * 8;

  auto STAGE = [&](int kt, unsigned short* A, unsigned short* B) {
    gload16(pA0 + kt, (char*)A + ldsOff);
    gload16(pA1 + kt, (char*)A + 4096 + ldsOff);
    gload16(pB0 + kt, (char*)B + ldsOff);
    gload16(pB1 + kt, (char*)B + 4096 + ldsOff);
  };
  auto COMPUTE = [&](const unsigned short* A, const unsigned short* B) {
    bf16x8 af[4], bfr[4];
#pragma unroll
    for (int m = 0; m < 4; m++)
      af[m] = *reinterpret_cast<const bf16x8*>(A + (wr*64 + m*16 + frow) * BK + kb);
#pragma unroll
    for (int n = 0; n < 4; n++)
      bfr[n] = *reinterpret_cast<const bf16x8*>(B + (wc*64 + n*16 + frow) * BK + kb);
#pragma unroll
    for (int m = 0; m < 4; m++)
#pragma unroll
      for (int n = 0; n < 4; n++)
        acc[m][n] = __builtin_amdgcn_mfma_f32_16x16x32_bf16(af[m], bfr[n], acc[m][n], 0, 0, 0);
    WAITL();
    BAR();
  };

  STAGE(0, As0, Bs0);
  int ks = BK;
  // NT = HID/BK = 128 steps -> 63 double-iterations + tail pair
  for (int i = 0; i < 63; i++) {
    STAGE(ks, As1, Bs1); ks += BK;
    WAITV(4); BAR();
    COMPUTE(As0, Bs0);
    STAGE(ks, As0, Bs0); ks += BK;
    WAITV(4); BAR();
    COMPUTE(As1, Bs1);
  }
  STAGE(ks, As1, Bs1);
  WAITV(4); BAR();
  COMPUTE(As0, Bs0);
  WAITV(0); BAR();
  COMPUTE(As1, Bs1);

  const int crow = (l >> 4) * 4;
  const int ccol = l & 15;
  float bias[4];
#pragma unroll
  for (int n = 0; n < 4; n++) bias[n] = b2[(size_t)e * DIM + n0 + wc*64 + n*16 + ccol];

#pragma unroll
  for (int m = 0; m < 4; m++) {
#pragma unroll
    for (int j = 0; j < 4; j++) {
      int r = wr*64 + m*16 + crow + j;
      if (r < rows_valid) {
        int pos = row_start + r;
        float wv = pair_w[pos];
#pragma unroll
        for (int n = 0; n < 4; n++)
          y[(size_t)pos * DIM + n0 + wc*64 + n*16 + ccol] = f2bf((acc[m][n][j] + bias[n]) * wv);
      }
    }
  }
}

// ---------------- combine ----------------
__global__ __launch_bounds__(256) void combine_kernel(const unsigned short* __restrict__ y,
                                                      const int* __restrict__ pos_of,
                                                      float* __restrict__ out)
{
  const int t = blockIdx.x * 4 + (threadIdx.x >> 6);
  const int lane = threadIdx.x & 63;
  const int p0 = pos_of[2*t], p1 = pos_of[2*t+1];
  const unsigned short* a = y + (size_t)p0 * DIM;
  const unsigned short* b = y + (size_t)p1 * DIM;
  float* o = out + (size_t)t * DIM;
#pragma unroll
  for (int i = 0; i < 4; i++) {
    int d = i * 256 + lane * 4;
    unsigned long long va = *reinterpret_cast<const unsigned long long*>(a + d);
    unsigned long long vb = *reinterpret_cast<const unsigned long long*>(b + d);
    f32x4 r;
#pragma unroll
    for (int k = 0; k < 4; k++)
      r[k] = bf2f((unsigned short)(va >> (16*k))) + bf2f((unsigned short)(vb >> (16*k)));
    *reinterpret_cast<f32x4*>(o + d) = r;
  }
}

extern "C" void kernel_launch(void* const* d_in, const int* in_sizes, int n_in,
                              void* d_out, int out_size, void* d_ws, size_t ws_size,
                              hipStream_t stream) {
  const float* x  = (const float*)d_in[0];
  const float* Wg = (const float*)d_in[1];
  const float* bg = (const float*)d_in[2];
  const float* W1 = (const float*)d_in[3];
  const float* b1 = (const float*)d_in[4];
  const float* W2 = (const float*)d_in[5];
  const float* b2 = (const float*)d_in[6];
  float* out = (float*)d_out;

  char* ws = (char*)d_ws;
  const size_t MB = 1024 * 1024;
  int*   expert_count  = (int*)(ws + 0);
  int*   nt1           = (int*)(ws + 64);
  int*   nt2           = (int*)(ws + 68);
  int*   expert_offset = (int*)(ws + 128);
  int*   table1        = (int*)(ws + 256);
  int*   table2        = (int*)(ws + 2048);
  int*   topk_idx      = (int*)(ws + 4096);
  float* topk_w        = (float*)(ws + 4096 + 32768);
  int*   pair_token    = (int*)(ws + 4096 + 65536);
  float* pair_w        = (float*)(ws + 4096 + 98304);
  int*   pos_of        = (int*)(ws + 4096 + 131072);
  unsigned short* xb   = (unsigned short*)(ws + 1*MB);    //  8 MiB
  unsigned short* y    = (unsigned short*)(ws + 9*MB);    // 16 MiB
  unsigned short* Wt   = (unsigned short*)(ws + 25*MB);   // 64 MiB (Wt1, then Wt2)
  unsigned short* h    = (unsigned short*)(ws + 89*MB);   // 64 MiB

  hipMemsetAsync(ws, 0, 256, stream);

  gate_kernel<<<N_TOK / 4, 256, 0, stream>>>(x, Wg, bg, topk_idx, topk_w, expert_count);
  scan_kernel<<<1, 64, 0, stream>>>(expert_count, expert_offset, table1, nt1, table2, nt2);
  scatter_kernel<<<1, 512, 0, stream>>>(topk_idx, topk_w, expert_offset,
                                        pair_token, pair_w, pos_of);
  xconv_kernel<<<(N_TOK * DIM) / (256 * 4), 256, 0, stream>>>(x, xb);
  transpose_kernel<<<dim3(HID/64, DIM/64, NEXP), 256, 0, stream>>>(W1, Wt, DIM, HID);
  ffn1_kernel<<<MAXT1 * 32, 512, 0, stream>>>(xb, Wt, b1, pair_token, table1, nt1, h);
  transpose_kernel<<<dim3(DIM/64, HID/64, NEXP), 256, 0, stream>>>(W2, Wt, HID, DIM);
  ffn2_kernel<<<MAXT2 * 8, 256, 0, stream>>>(h, Wt, b2, pair_w, table2, nt2, y);
  combine_kernel<<<N_TOK / 4, 256, 0, stream>>>(y, pos_of, out);
}